// Round 4
// baseline (1321.305 us; speedup 1.0000x reference)
//
#include <hip/hip_runtime.h>

// MLA forward. Inputs/outputs fp32 (per reference); internal compute bf16 MFMA.
// B=2 T=2048 C=2048 NH=16 HS=128 NLQ=NLKV=512 DHR=64
//
// Fragment layouts (gfx950, verified per learn_hip m89/m120):
//   A[m][k]: m = lane&15, k = (lane>>4)*8 + j   (8 bf16 / lane)
//   B[k][n]: n = lane&15, k = (lane>>4)*8 + j
//   C/D[row][col]: col = lane&15, row = (lane>>4)*4 + reg

typedef __bf16 bf16;
typedef __bf16 bf16x8 __attribute__((ext_vector_type(8)));
typedef __bf16 bf16x4 __attribute__((ext_vector_type(4)));
typedef float f32x4 __attribute__((ext_vector_type(4)));
typedef unsigned short u16x4v __attribute__((ext_vector_type(4)));
typedef unsigned short u16x8v __attribute__((ext_vector_type(8)));

#define MFMA16(a, b, c) __builtin_amdgcn_mfma_f32_16x16x32_bf16((a), (b), (c), 0, 0, 0)

// async global->LDS 16B (linear dest: wave-uniform base + lane*16)
__device__ __forceinline__ void stage16(const bf16* g, bf16* lds)
{
    __builtin_amdgcn_global_load_lds(
        (const __attribute__((address_space(1))) unsigned int*)g,
        (__attribute__((address_space(3))) unsigned int*)lds,
        16, 0, 0);
}

// hardware transpose read: two ds_read_b64_tr_b16 covering one 8x16 bf16 subtile
// (two stacked 4x16 tiles, 128 B apart). Per 16-lane group, lane addr =
// window_base + l16*8 bytes; delivered elem j = window[j*16 + l16].
__device__ __forceinline__ void tr_pair(unsigned addr, u16x4v& lo, u16x4v& hi)
{
    asm volatile("ds_read_b64_tr_b16 %0, %2\n\t"
                 "ds_read_b64_tr_b16 %1, %2 offset:128"
                 : "=&v"(lo), "=&v"(hi)
                 : "v"(addr)
                 : "memory");
}

__device__ __forceinline__ bf16x8 bv8(u16x4v lo, u16x4v hi)
{
    u16x8v u = __builtin_shufflevector(lo, hi, 0, 1, 2, 3, 4, 5, 6, 7);
    return __builtin_bit_cast(bf16x8, u);
}

// ---------------------------------------------------------------------------
// fp32 -> bf16 batched conversion (9 tensors, descriptor struct by value)
// ---------------------------------------------------------------------------
struct CvtDesc { const float* src; bf16* dst; long long n4; };
struct CvtArgs { CvtDesc d[9]; };

__global__ void convert_many(CvtArgs a)
{
    CvtDesc d = a.d[blockIdx.y];
    long long i = (long long)blockIdx.x * blockDim.x + threadIdx.x;
    long long stride = (long long)gridDim.x * blockDim.x;
    for (; i < d.n4; i += stride) {
        f32x4 v = ((const f32x4*)d.src)[i];
        bf16x4 o;
        o[0] = (bf16)v[0]; o[1] = (bf16)v[1]; o[2] = (bf16)v[2]; o[3] = (bf16)v[3];
        ((bf16x4*)d.dst)[i] = o;
    }
}

// ---------------------------------------------------------------------------
// NT GEMM: C[z][m][n] = sum_k A[m*lda+k] * B[n*ldb+k]   (both K-contiguous)
// Block: 256 thr = 4 waves; tile 64(M) x 64(N); wave w owns rows w*16..w*16+15.
// A and B K-tiles (64x32 each) staged once into LDS via global_load_lds.
// ---------------------------------------------------------------------------
template <typename OutT>
__global__ __launch_bounds__(256, 4)
void gemm_nt(const bf16* __restrict__ A, const bf16* __restrict__ B,
             OutT* __restrict__ C, int K, int lda, int ldb, int ldc,
             long long sAb, long long sAh, long long sBb, long long sBh,
             long long sCb, long long sCh, int ZH)
{
    __shared__ __attribute__((aligned(16))) bf16 As[64 * 32];  // [m_local][k_local]
    __shared__ __attribute__((aligned(16))) bf16 Bs[64 * 32];  // [n_local][k_local]

    int z = blockIdx.z;
    int bb = z / ZH, hh = z % ZH;
    A += bb * sAb + hh * sAh;
    B += bb * sBb + hh * sBh;
    C += bb * sCb + hh * sCh;

    int tid = threadIdx.x;
    int w = tid >> 6, lane = tid & 63, l16 = lane & 15, quad = lane >> 4;
    int m0 = blockIdx.x * 64;
    int n0 = blockIdx.y * 64;

    int srow = w * 16 + (lane >> 2);
    int scol = (lane & 3) * 8;
    const bf16* gA = A + (long long)(m0 + srow) * lda + scol;
    const bf16* gB = B + (long long)(n0 + srow) * ldb + scol;
    bf16* lA = As + w * 512;   // wave-uniform dest base
    bf16* lB = Bs + w * 512;

    const bf16* fA = As + (w * 16 + l16) * 32 + quad * 8;
    f32x4 acc[4] = {};

    for (int k = 0; k < K; k += 32) {
        __syncthreads();
        stage16(gA + k, lA);
        stage16(gB + k, lB);
        __syncthreads();   // compiler drains vmcnt before barrier

        bf16x8 a = *(const bf16x8*)fA;
#pragma unroll
        for (int nt = 0; nt < 4; ++nt) {
            bf16x8 b = *(const bf16x8*)(Bs + (nt * 16 + l16) * 32 + quad * 8);
            acc[nt] = MFMA16(a, b, acc[nt]);
        }
    }
#pragma unroll
    for (int nt = 0; nt < 4; ++nt)
#pragma unroll
        for (int r = 0; r < 4; ++r) {
            int row = m0 + w * 16 + quad * 4 + r;
            int col = n0 + nt * 16 + l16;
            C[(long long)row * ldc + col] = (OutT)acc[nt][r];
        }
}

// ---------------------------------------------------------------------------
// NN GEMM: C[z][m][n] = sum_k A[m*lda+k] * B[k*ldb+n]
// B K-tile (32 x 64) staged via global_load_lds into the 4x16-subtiled layout;
// B-fragments read via ds_read_b64_tr_b16 pairs. A rows from global.
// ---------------------------------------------------------------------------
__global__ __launch_bounds__(256, 4)
void gemm_nn(const bf16* __restrict__ A, const bf16* __restrict__ B,
             bf16* __restrict__ C, int K, int lda, int ldb, int ldc,
             long long sAb, long long sAh, long long sBb, long long sBh,
             long long sCb, long long sCh, int ZH)
{
    __shared__ __attribute__((aligned(16))) bf16 BTs[2048];  // 4 KB subtiled

    int z = blockIdx.z;
    int bb = z / ZH, hh = z % ZH;
    A += bb * sAb + hh * sAh;
    B += bb * sBb + hh * sBh;
    C += bb * sCb + hh * sCh;

    int tid = threadIdx.x;
    int w = tid >> 6, lane = tid & 63, l16 = lane & 15, quad = lane >> 4;
    int m0 = blockIdx.x * 64;
    int n0 = blockIdx.y * 64;

    int srow = (lane >> 3) * 4 + ((lane >> 1) & 3);   // k row 0..31
    int scol = (lane & 1) * 8;                        // 0 or 8 within 16-col tile
    const bf16* gB = B + (long long)srow * ldb + n0 + w * 16 + scol;
    bf16* lB = BTs + w * 512;   // wave w stages col-tile w (1024 B)

    const bf16* Arow = A + (long long)(m0 + w * 16 + l16) * lda;
    unsigned trb = (unsigned)(unsigned long long)(const void*)BTs
                 + (unsigned)(quad * 256 + l16 * 8);

    f32x4 acc[4] = {};

    for (int k = 0; k < K; k += 32) {
        __syncthreads();
        stage16(gB + (long long)k * ldb, lB);
        __syncthreads();

        bf16x8 a = *(const bf16x8*)(Arow + k + quad * 8);
        u16x4v L0, H0, L1, H1, L2, H2, L3, H3;
        tr_pair(trb,        L0, H0);
        tr_pair(trb + 1024, L1, H1);
        tr_pair(trb + 2048, L2, H2);
        tr_pair(trb + 3072, L3, H3);
        asm volatile("s_waitcnt lgkmcnt(0)" ::: "memory");
        __builtin_amdgcn_sched_barrier(0);
        acc[0] = MFMA16(a, bv8(L0, H0), acc[0]);
        acc[1] = MFMA16(a, bv8(L1, H1), acc[1]);
        acc[2] = MFMA16(a, bv8(L2, H2), acc[2]);
        acc[3] = MFMA16(a, bv8(L3, H3), acc[3]);
    }
#pragma unroll
    for (int nt = 0; nt < 4; ++nt)
#pragma unroll
        for (int r = 0; r < 4; ++r) {
            int row = m0 + w * 16 + quad * 4 + r;
            int col = n0 + nt * 16 + l16;
            C[(long long)row * ldc + col] = (bf16)acc[nt][r];
        }
}

// ---------------------------------------------------------------------------
// RoPE kernels: write rotated halves into cols 512..575 of Kcat / Qcat.
// ---------------------------------------------------------------------------
__global__ void rope_k_kernel(const bf16* __restrict__ krr, const float* __restrict__ cosb,
                              const float* __restrict__ sinb, bf16* __restrict__ Kcat)
{
    int i = blockIdx.x * 256 + threadIdx.x;  // B*T*32 = 131072
    int pr = i & 31;
    int row = i >> 5;            // b*2048 + t
    int t = row & 2047;
    float re = (float)krr[row * 64 + 2 * pr];
    float im = (float)krr[row * 64 + 2 * pr + 1];
    float c = cosb[t * 32 + pr];
    float s = sinb[t * 32 + pr];
    long long base = (long long)row * 576 + 512 + 2 * pr;
    Kcat[base]     = (bf16)(re * c - im * s);
    Kcat[base + 1] = (bf16)(re * s + im * c);
}

__global__ void rope_q_kernel(const bf16* __restrict__ qrr, const float* __restrict__ cosb,
                              const float* __restrict__ sinb, bf16* __restrict__ Qcat)
{
    int i = blockIdx.x * 256 + threadIdx.x;  // B*T*NH*32 = 4194304
    int pr = i & 31;
    int h = (i >> 5) & 15;
    int t = (i >> 9) & 2047;
    int b = i >> 20;
    long long src = ((long long)(b * 2048 + t)) * 1024 + h * 64 + 2 * pr;
    float re = (float)qrr[src];
    float im = (float)qrr[src + 1];
    float c = cosb[t * 32 + pr];
    float s = sinb[t * 32 + pr];
    long long dst = ((long long)((b * 16 + h) * 2048 + t)) * 576 + 512 + 2 * pr;
    Qcat[dst]     = (bf16)(re * c - im * s);
    Qcat[dst + 1] = (bf16)(re * s + im * c);
}

// ---------------------------------------------------------------------------
// Causal flash attention (MLA absorbed form).
// Q per (b,h): Qcat[z] (2048 x 576). K per b: Kcat[b] (2048 x 576).
// V = Kcat[:, 0:512]. O -> ctx[z] (2048 x 512), already /l.
// Block: 256 thr (4 waves), 64 Q rows / block, KV tile = 32.
//
// Occupancy is structurally 1 wave/SIMD (o[32] = 128 AGPR + arch VGPR > 256),
// so all latency must be removed from the single resident wave:
//   * Q fragments hoisted to registers ONCE per block (no per-tile global Q)
//   * KT double-buffered: stage(t+1) issued before compute(t), vmcnt drained
//     only at end of iteration (T3 2-phase prefetch)
//   * defer-max (T13, THR=8): skip o-rescale when running max doesn't grow
// ---------------------------------------------------------------------------
#define ATTN_SCALE 0.07216878364870322f  // 1/sqrt(192)

__global__ __launch_bounds__(256, 1)
void flash_mla(const bf16* __restrict__ Qcat, const bf16* __restrict__ Kcat,
               bf16* __restrict__ ctx)
{
    __shared__ __attribute__((aligned(16))) bf16 KT[2][288 * 64];  // 2 x 36 KB
    __shared__ __attribute__((aligned(16))) bf16 P[4][16 * 40];    // per-wave P strip

    const int T = 2048;
    int z = blockIdx.y;          // b*16 + h
    int b = z >> 4;
    int qt = blockIdx.x;
    int tid = threadIdx.x;
    int w = tid >> 6, lane = tid & 63, l16 = lane & 15, quad = lane >> 4;

    const bf16* Qb = Qcat + (long long)z * T * 576;
    const bf16* Kb = Kcat + (long long)b * T * 576;
    bf16* Ob = ctx + (long long)z * T * 512;

    int qbase = qt * 64;
    const bf16* Qrow = Qb + (long long)(qbase + w * 16 + l16) * 576;

    // hoist Q fragments to registers (one-time, reused every KV tile)
    bf16x8 q[18];
#pragma unroll
    for (int kk = 0; kk < 18; ++kk)
        q[kk] = *(const bf16x8*)(Qrow + kk * 32 + quad * 8);

    // staging source mapping (per lane): linear-dest order of the subtiled layout
    int srow = (lane >> 3) * 4 + ((lane >> 1) & 3);   // 0..31
    int scol = (lane & 1) * 8;                        // 0 or 8

    // QK^T B-fragment offset (elements within one KT buffer)
    int kqoff = ((quad >> 1) * 8 + (l16 >> 2)) * 64 + (l16 & 3) * 16 + (quad & 1) * 8;
    // PV tr-read offset (bytes within one KT buffer)
    unsigned ldsKT = (unsigned)(unsigned long long)(const void*)&KT[0][0];
    unsigned troff = (unsigned)(quad * 256 + l16 * 8);

    f32x4 o[32] = {};
    float mrow[4], lrow[4];
#pragma unroll
    for (int r = 0; r < 4; ++r) { mrow[r] = -1e30f; lrow[r] = 0.f; }

    int ntiles = (qbase + 64) >> 5;

    // prologue: stage tile 0 into buffer 0
    {
        const bf16* gs = Kb + (long long)srow * 576 + scol;
#pragma unroll
        for (int it = 0; it < 9; ++it) {
            int ci = it * 4 + w;
            stage16(gs + ci * 16, &KT[0][ci * 512]);
        }
    }
    asm volatile("s_waitcnt vmcnt(0)" ::: "memory");
    __syncthreads();

    int cur = 0;
    for (int st = 0; st < ntiles; ++st) {
        int s0 = st << 5;

        // issue prefetch of next tile into the other buffer (async)
        if (st + 1 < ntiles) {
            const bf16* gs = Kb + (long long)(s0 + 32 + srow) * 576 + scol;
#pragma unroll
            for (int it = 0; it < 9; ++it) {
                int ci = it * 4 + w;
                stage16(gs + ci * 16, &KT[cur ^ 1][ci * 512]);
            }
        }

        // QK^T: 16 rows x 32 cols, K = 576 = 18 steps; Q from regs, K from LDS
        const bf16* kq0 = &KT[cur][kqoff];
        f32x4 sa = {0.f, 0.f, 0.f, 0.f}, sb = {0.f, 0.f, 0.f, 0.f};
        __builtin_amdgcn_s_setprio(1);
#pragma unroll
        for (int kk = 0; kk < 18; ++kk) {
            bf16x8 b0 = *(const bf16x8*)(kq0 + kk * 1024);        // rows l16
            bf16x8 b1 = *(const bf16x8*)(kq0 + kk * 1024 + 256);  // rows 16+l16
            sa = MFMA16(q[kk], b0, sa);
            sb = MFMA16(q[kk], b1, sb);
        }
        __builtin_amdgcn_s_setprio(0);

        // online softmax with defer-max (rows r = quad*4+0..3, cols s0+{0,16}+l16)
        float v0[4], v1[4], rm4[4];
#pragma unroll
        for (int r = 0; r < 4; ++r) {
            int trow = qbase + w * 16 + quad * 4 + r;
            float a0 = sa[r] * ATTN_SCALE;
            float a1 = sb[r] * ATTN_SCALE;
            if (s0 + l16 > trow)      a0 = -1e30f;
            if (s0 + 16 + l16 > trow) a1 = -1e30f;
            v0[r] = a0; v1[r] = a1;
            float rm = fmaxf(a0, a1);
#pragma unroll
            for (int off = 1; off < 16; off <<= 1)
                rm = fmaxf(rm, __shfl_xor(rm, off, 64));
            rm4[r] = rm;
        }
        bool dfr = true;
#pragma unroll
        for (int r = 0; r < 4; ++r) dfr = dfr && (rm4[r] - mrow[r] <= 8.f);
        bool allDefer = __all(dfr);

        float alpha[4];
        if (!allDefer) {
#pragma unroll
            for (int r = 0; r < 4; ++r) {
                float mnew = fmaxf(mrow[r], rm4[r]);
                alpha[r] = __expf(mrow[r] - mnew);
                mrow[r] = mnew;
            }
        }
#pragma unroll
        for (int r = 0; r < 4; ++r) {
            float p0 = __expf(v0[r] - mrow[r]);
            float p1 = __expf(v1[r] - mrow[r]);
            float rs = p0 + p1;
#pragma unroll
            for (int off = 1; off < 16; off <<= 1)
                rs += __shfl_xor(rs, off, 64);
            lrow[r] = (allDefer ? lrow[r] : lrow[r] * alpha[r]) + rs;
            P[w][(quad * 4 + r) * 40 + l16]      = (bf16)p0;
            P[w][(quad * 4 + r) * 40 + 16 + l16] = (bf16)p1;
        }

        // rescale O only when the running max actually grew (wave-uniform)
        if (!allDefer) {
#pragma unroll
            for (int nt = 0; nt < 32; ++nt)
#pragma unroll
                for (int r = 0; r < 4; ++r) o[nt][r] *= alpha[r];
        }

        bf16x8 pa = *(const bf16x8*)(&P[w][l16 * 40 + quad * 8]);
        // drain P writes + pa before starting counted tr-read pipeline
        asm volatile("s_waitcnt lgkmcnt(0)" ::: "memory");
        __builtin_amdgcn_sched_barrier(0);

        // PV: software-pipelined (depth 2, 3-slot ring) hardware-transpose reads
        unsigned trbase = ldsKT + (unsigned)(cur * 36864) + troff;
        u16x4v L[3], H[3];
        tr_pair(trbase,        L[0], H[0]);
        tr_pair(trbase + 1024, L[1], H[1]);
        __builtin_amdgcn_s_setprio(1);
#pragma unroll
        for (int nt = 0; nt < 32; ++nt) {
            if (nt < 30) {
                tr_pair(trbase + (unsigned)((nt + 2) * 1024), L[(nt + 2) % 3], H[(nt + 2) % 3]);
                asm volatile("s_waitcnt lgkmcnt(4)" ::: "memory");
            } else if (nt == 30) {
                asm volatile("s_waitcnt lgkmcnt(2)" ::: "memory");
            } else {
                asm volatile("s_waitcnt lgkmcnt(0)" ::: "memory");
            }
            __builtin_amdgcn_sched_barrier(0);
            o[nt] = MFMA16(pa, bv8(L[nt % 3], H[nt % 3]), o[nt]);
        }
        __builtin_amdgcn_s_setprio(0);

        // end of iteration: my prefetch loads done; everyone done reading cur
        asm volatile("s_waitcnt vmcnt(0)" ::: "memory");
        __syncthreads();
        cur ^= 1;
    }

    // epilogue: normalize and store ctx
#pragma unroll
    for (int nt = 0; nt < 32; ++nt)
#pragma unroll
        for (int r = 0; r < 4; ++r) {
            int trow = qbase + w * 16 + quad * 4 + r;
            Ob[(long long)trow * 512 + nt * 16 + l16] = (bf16)(o[nt][r] / lrow[r]);
        }
}

// ---------------------------------------------------------------------------
extern "C" void kernel_launch(void* const* d_in, const int* in_sizes, int n_in,
                              void* d_out, int out_size, void* d_ws, size_t ws_size,
                              hipStream_t stream)
{
    const float* xf    = (const float*)d_in[0];
    const float* cosb  = (const float*)d_in[1];
    const float* sinb  = (const float*)d_in[2];
    const float* Wdqf  = (const float*)d_in[3];
    const float* Wuqf  = (const float*)d_in[4];
    const float* Wdkvf = (const float*)d_in[5];
    const float* Wukf  = (const float*)d_in[6];
    const float* Wuvf  = (const float*)d_in[7];
    const float* Wqrf  = (const float*)d_in[8];
    const float* Wkrf  = (const float*)d_in[9];
    const float* Wof   = (const float*)d_in[10];
    float* y = (float*)d_out;

    // workspace carve-up (bf16 intermediates + bf16 input copies, ~206 MB)
    char* ws = (char*)d_ws;
    bf16* c_q  = (bf16*)ws; ws += (size_t)4096 * 512 * 2;        // 4 MB
    bf16* Kcat = (bf16*)ws; ws += (size_t)4096 * 576 * 2;        // 4.7 MB
    bf16* krr  = (bf16*)ws; ws += (size_t)4096 * 64 * 2;         // 0.5 MB
    bf16* qrr  = (bf16*)ws; ws += (size_t)4096 * 1024 * 2;       // 8 MB
    bf16* vC2  = (bf16*)ws; ws += (size_t)2048 * 512 * 2;        // 2 MB
    bf16* keff = (bf16*)ws; ws += (size_t)16 * 512 * 512 * 2;    // 8 MB
    bf16* Qcat = (bf16*)ws; ws += (size_t)32 * 2048 * 576 * 2;   // 75.5 MB
    bf16* ctx  = (bf16*)ws; ws += (size_t)32 * 2048 * 512 * 2;   // 67 MB
    bf16* x    = (bf16*)ws; ws += (size_t)4096 * 2048 * 2;       // 16.8 MB
    bf16* Wdq  = (bf16*)ws; ws += (size_t)512 * 2048 * 2;        // 2 MB
    bf16* Wuq  = (bf16*)ws; ws += (size_t)2048 * 512 * 2;        // 2 MB
    bf16* Wdkv = (bf16*)ws; ws += (size_t)512 * 2048 * 2;        // 2 MB
    bf16* Wuk  = (bf16*)ws; ws += (size_t)2048 * 512 * 2;        // 2 MB
    bf16* Wuv  = (bf16*)ws; ws += (size_t)2048 * 512 * 2;        // 2 MB
    bf16* Wqr  = (bf16*)ws; ws += (size_t)1024 * 512 * 2;        // 1 MB
    bf16* Wkr  = (bf16*)ws; ws += (size_t)64 * 2048 * 2;         // 0.25 MB
    bf16* Wo   = (bf16*)ws; ws += (size_t)2048 * 2048 * 2;       // 8 MB

    dim3 blk(256);

    // 0. fp32 -> bf16 conversion of all matmul operands
    CvtArgs ca;
    ca.d[0] = {xf,    x,    (long long)4096 * 2048 / 4};
    ca.d[1] = {Wdqf,  Wdq,  (long long)512 * 2048 / 4};
    ca.d[2] = {Wuqf,  Wuq,  (long long)2048 * 512 / 4};
    ca.d[3] = {Wdkvf, Wdkv, (long long)512 * 2048 / 4};
    ca.d[4] = {Wukf,  Wuk,  (long long)2048 * 512 / 4};
    ca.d[5] = {Wuvf,  Wuv,  (long long)2048 * 512 / 4};
    ca.d[6] = {Wqrf,  Wqr,  (long long)1024 * 512 / 4};
    ca.d[7] = {Wkrf,  Wkr,  (long long)64 * 2048 / 4};
    ca.d[8] = {Wof,   Wo,   (long long)2048 * 2048 / 4};
    convert_many<<<dim3(512, 9), blk, 0, stream>>>(ca);

    // 1. c_q = x @ Wdq^T                       (4096 x 512, K=2048)
    gemm_nt<bf16><<<dim3(64, 8, 1), blk, 0, stream>>>(x, Wdq, c_q, 2048, 2048, 2048, 512,
                                                      0, 0, 0, 0, 0, 0, 1);
    // 2. c_kv -> Kcat[:, 0:512]                (4096 x 512, ldc=576)
    gemm_nt<bf16><<<dim3(64, 8, 1), blk, 0, stream>>>(x, Wdkv, Kcat, 2048, 2048, 2048, 576,
                                                      0, 0, 0, 0, 0, 0, 1);
    // 3. k_r_raw = x @ Wkr^T                   (4096 x 64)
    gemm_nt<bf16><<<dim3(64, 1, 1), blk, 0, stream>>>(x, Wkr, krr, 2048, 2048, 2048, 64,
                                                      0, 0, 0, 0, 0, 0, 1);
    // 4. q_r_raw = c_q @ Wqr^T                 (4096 x 1024, K=512)
    gemm_nt<bf16><<<dim3(64, 16, 1), blk, 0, stream>>>(c_q, Wqr, qrr, 512, 512, 512, 1024,
                                                       0, 0, 0, 0, 0, 0, 1);
    // 5. vC2 = Wo @ Wuv                        (2048 x 512, K=2048, NN)
    gemm_nn<<<dim3(32, 8, 1), blk, 0, stream>>>(Wo, Wuv, vC2, 2048, 2048, 512, 512,
                                                0, 0, 0, 0, 0, 0, 1);
    // 6. k_eff[h] = Wuq_r[h] @ Wuk_r[h]        (Z=16, 512 x 512, K=128, NN)
    gemm_nn<<<dim3(8, 8, 16), blk, 0, stream>>>(Wuq, Wuk, keff, 128, 2048, 512, 512,
                                                0, 128, 0, 65536, 0, 262144, 16);
    // 7. q_lat -> Qcat[:, 0:512]               (Z=32, 2048 x 512, K=512, NN)
    gemm_nn<<<dim3(32, 8, 32), blk, 0, stream>>>(c_q, keff, Qcat, 512, 512, 512, 576,
                                                 (long long)2048 * 512, 0,
                                                 0, 262144,
                                                 (long long)16 * 2048 * 576,
                                                 (long long)2048 * 576, 16);
    // 8. RoPE
    rope_k_kernel<<<dim3(512), blk, 0, stream>>>(krr, cosb, sinb, Kcat);
    rope_q_kernel<<<dim3(16384), blk, 0, stream>>>(qrr, cosb, sinb, Qcat);
    // 9. flash attention -> ctx
    flash_mla<<<dim3(32, 32), blk, 0, stream>>>(Qcat, Kcat, ctx);
    // 10. y[b,t,h*128+d] = sum_k ctx[b,h,t,k] * vC2[h*128+d,k]   (Z=32, NT, fp32 out)
    gemm_nt<float><<<dim3(32, 2, 32), blk, 0, stream>>>(ctx, vC2, y, 512, 512, 512, 2048,
                                                        (long long)16 * 2048 * 512,
                                                        (long long)2048 * 512,
                                                        0, 65536,
                                                        (long long)2048 * 2048, 128, 16);
}

// Round 5
// 696.893 us; speedup vs baseline: 1.8960x; 1.8960x over previous
//
#include <hip/hip_runtime.h>

// MLA forward. Inputs/outputs fp32 (per reference); internal compute bf16 MFMA.
// B=2 T=2048 C=2048 NH=16 HS=128 NLQ=NLKV=512 DHR=64
//
// Fragment layouts (gfx950, verified per learn_hip m89/m120):
//   A[m][k]: m = lane&15, k = (lane>>4)*8 + j   (8 bf16 / lane)
//   B[k][n]: n = lane&15, k = (lane>>4)*8 + j
//   C/D[row][col]: col = lane&15, row = (lane>>4)*4 + reg

typedef __bf16 bf16;
typedef __bf16 bf16x8 __attribute__((ext_vector_type(8)));
typedef __bf16 bf16x4 __attribute__((ext_vector_type(4)));
typedef float f32x4 __attribute__((ext_vector_type(4)));
typedef unsigned short u16x4v __attribute__((ext_vector_type(4)));
typedef unsigned short u16x8v __attribute__((ext_vector_type(8)));

#define MFMA16(a, b, c) __builtin_amdgcn_mfma_f32_16x16x32_bf16((a), (b), (c), 0, 0, 0)

// async global->LDS 16B (linear dest: wave-uniform base + lane*16)
__device__ __forceinline__ void stage16(const bf16* g, bf16* lds)
{
    __builtin_amdgcn_global_load_lds(
        (const __attribute__((address_space(1))) unsigned int*)g,
        (__attribute__((address_space(3))) unsigned int*)lds,
        16, 0, 0);
}

// hardware transpose read: two ds_read_b64_tr_b16 covering one 8x16 bf16 subtile
// (two stacked 4x16 tiles, 128 B apart). Per 16-lane group, lane addr =
// window_base + l16*8 bytes; delivered elem j = window[j*16 + l16].
__device__ __forceinline__ void tr_pair(unsigned addr, u16x4v& lo, u16x4v& hi)
{
    asm volatile("ds_read_b64_tr_b16 %0, %2\n\t"
                 "ds_read_b64_tr_b16 %1, %2 offset:128"
                 : "=&v"(lo), "=&v"(hi)
                 : "v"(addr)
                 : "memory");
}

__device__ __forceinline__ bf16x8 bv8(u16x4v lo, u16x4v hi)
{
    u16x8v u = __builtin_shufflevector(lo, hi, 0, 1, 2, 3, 4, 5, 6, 7);
    return __builtin_bit_cast(bf16x8, u);
}

// ---------------------------------------------------------------------------
// fp32 -> bf16 batched conversion (9 tensors, descriptor struct by value)
// ---------------------------------------------------------------------------
struct CvtDesc { const float* src; bf16* dst; long long n4; };
struct CvtArgs { CvtDesc d[9]; };

__global__ void convert_many(CvtArgs a)
{
    CvtDesc d = a.d[blockIdx.y];
    long long i = (long long)blockIdx.x * blockDim.x + threadIdx.x;
    long long stride = (long long)gridDim.x * blockDim.x;
    for (; i < d.n4; i += stride) {
        f32x4 v = ((const f32x4*)d.src)[i];
        bf16x4 o;
        o[0] = (bf16)v[0]; o[1] = (bf16)v[1]; o[2] = (bf16)v[2]; o[3] = (bf16)v[3];
        ((bf16x4*)d.dst)[i] = o;
    }
}

// ---------------------------------------------------------------------------
// NT GEMM: C[z][m][n] = sum_k A[m*lda+k] * B[n*ldb+k]   (both K-contiguous)
// Block: 256 thr = 4 waves; tile 64(M) x 64(N); wave w owns rows w*16..w*16+15.
// A and B K-tiles (64x32 each) staged once into LDS via global_load_lds.
// ---------------------------------------------------------------------------
template <typename OutT>
__global__ __launch_bounds__(256, 4)
void gemm_nt(const bf16* __restrict__ A, const bf16* __restrict__ B,
             OutT* __restrict__ C, int K, int lda, int ldb, int ldc,
             long long sAb, long long sAh, long long sBb, long long sBh,
             long long sCb, long long sCh, int ZH)
{
    __shared__ __attribute__((aligned(16))) bf16 As[64 * 32];  // [m_local][k_local]
    __shared__ __attribute__((aligned(16))) bf16 Bs[64 * 32];  // [n_local][k_local]

    int z = blockIdx.z;
    int bb = z / ZH, hh = z % ZH;
    A += bb * sAb + hh * sAh;
    B += bb * sBb + hh * sBh;
    C += bb * sCb + hh * sCh;

    int tid = threadIdx.x;
    int w = tid >> 6, lane = tid & 63, l16 = lane & 15, quad = lane >> 4;
    int m0 = blockIdx.x * 64;
    int n0 = blockIdx.y * 64;

    int srow = w * 16 + (lane >> 2);
    int scol = (lane & 3) * 8;
    const bf16* gA = A + (long long)(m0 + srow) * lda + scol;
    const bf16* gB = B + (long long)(n0 + srow) * ldb + scol;
    bf16* lA = As + w * 512;   // wave-uniform dest base
    bf16* lB = Bs + w * 512;

    const bf16* fA = As + (w * 16 + l16) * 32 + quad * 8;
    f32x4 acc[4] = {};

    for (int k = 0; k < K; k += 32) {
        __syncthreads();
        stage16(gA + k, lA);
        stage16(gB + k, lB);
        __syncthreads();   // compiler drains vmcnt before barrier

        bf16x8 a = *(const bf16x8*)fA;
#pragma unroll
        for (int nt = 0; nt < 4; ++nt) {
            bf16x8 b = *(const bf16x8*)(Bs + (nt * 16 + l16) * 32 + quad * 8);
            acc[nt] = MFMA16(a, b, acc[nt]);
        }
    }
#pragma unroll
    for (int nt = 0; nt < 4; ++nt)
#pragma unroll
        for (int r = 0; r < 4; ++r) {
            int row = m0 + w * 16 + quad * 4 + r;
            int col = n0 + nt * 16 + l16;
            C[(long long)row * ldc + col] = (OutT)acc[nt][r];
        }
}

// ---------------------------------------------------------------------------
// NN GEMM: C[z][m][n] = sum_k A[m*lda+k] * B[k*ldb+n]
// B K-tile (32 x 64) staged via global_load_lds into the 4x16-subtiled layout;
// B-fragments read via ds_read_b64_tr_b16 pairs. A rows from global.
// ---------------------------------------------------------------------------
__global__ __launch_bounds__(256, 4)
void gemm_nn(const bf16* __restrict__ A, const bf16* __restrict__ B,
             bf16* __restrict__ C, int K, int lda, int ldb, int ldc,
             long long sAb, long long sAh, long long sBb, long long sBh,
             long long sCb, long long sCh, int ZH)
{
    __shared__ __attribute__((aligned(16))) bf16 BTs[2048];  // 4 KB subtiled

    int z = blockIdx.z;
    int bb = z / ZH, hh = z % ZH;
    A += bb * sAb + hh * sAh;
    B += bb * sBb + hh * sBh;
    C += bb * sCb + hh * sCh;

    int tid = threadIdx.x;
    int w = tid >> 6, lane = tid & 63, l16 = lane & 15, quad = lane >> 4;
    int m0 = blockIdx.x * 64;
    int n0 = blockIdx.y * 64;

    int srow = (lane >> 3) * 4 + ((lane >> 1) & 3);   // k row 0..31
    int scol = (lane & 1) * 8;                        // 0 or 8 within 16-col tile
    const bf16* gB = B + (long long)srow * ldb + n0 + w * 16 + scol;
    bf16* lB = BTs + w * 512;   // wave w stages col-tile w (1024 B)

    const bf16* Arow = A + (long long)(m0 + w * 16 + l16) * lda;
    unsigned trb = (unsigned)(unsigned long long)(const void*)BTs
                 + (unsigned)(quad * 256 + l16 * 8);

    f32x4 acc[4] = {};

    for (int k = 0; k < K; k += 32) {
        __syncthreads();
        stage16(gB + (long long)k * ldb, lB);
        __syncthreads();

        bf16x8 a = *(const bf16x8*)(Arow + k + quad * 8);
        u16x4v L0, H0, L1, H1, L2, H2, L3, H3;
        tr_pair(trb,        L0, H0);
        tr_pair(trb + 1024, L1, H1);
        tr_pair(trb + 2048, L2, H2);
        tr_pair(trb + 3072, L3, H3);
        asm volatile("s_waitcnt lgkmcnt(0)" ::: "memory");
        __builtin_amdgcn_sched_barrier(0);
        acc[0] = MFMA16(a, bv8(L0, H0), acc[0]);
        acc[1] = MFMA16(a, bv8(L1, H1), acc[1]);
        acc[2] = MFMA16(a, bv8(L2, H2), acc[2]);
        acc[3] = MFMA16(a, bv8(L3, H3), acc[3]);
    }
#pragma unroll
    for (int nt = 0; nt < 4; ++nt)
#pragma unroll
        for (int r = 0; r < 4; ++r) {
            int row = m0 + w * 16 + quad * 4 + r;
            int col = n0 + nt * 16 + l16;
            C[(long long)row * ldc + col] = (bf16)acc[nt][r];
        }
}

// ---------------------------------------------------------------------------
// RoPE kernels: write rotated halves into cols 512..575 of Kcat / Qcat.
// ---------------------------------------------------------------------------
__global__ void rope_k_kernel(const bf16* __restrict__ krr, const float* __restrict__ cosb,
                              const float* __restrict__ sinb, bf16* __restrict__ Kcat)
{
    int i = blockIdx.x * 256 + threadIdx.x;  // B*T*32 = 131072
    int pr = i & 31;
    int row = i >> 5;            // b*2048 + t
    int t = row & 2047;
    float re = (float)krr[row * 64 + 2 * pr];
    float im = (float)krr[row * 64 + 2 * pr + 1];
    float c = cosb[t * 32 + pr];
    float s = sinb[t * 32 + pr];
    long long base = (long long)row * 576 + 512 + 2 * pr;
    Kcat[base]     = (bf16)(re * c - im * s);
    Kcat[base + 1] = (bf16)(re * s + im * c);
}

__global__ void rope_q_kernel(const bf16* __restrict__ qrr, const float* __restrict__ cosb,
                              const float* __restrict__ sinb, bf16* __restrict__ Qcat)
{
    int i = blockIdx.x * 256 + threadIdx.x;  // B*T*NH*32 = 4194304
    int pr = i & 31;
    int h = (i >> 5) & 15;
    int t = (i >> 9) & 2047;
    int b = i >> 20;
    long long src = ((long long)(b * 2048 + t)) * 1024 + h * 64 + 2 * pr;
    float re = (float)qrr[src];
    float im = (float)qrr[src + 1];
    float c = cosb[t * 32 + pr];
    float s = sinb[t * 32 + pr];
    long long dst = ((long long)((b * 16 + h) * 2048 + t)) * 576 + 512 + 2 * pr;
    Qcat[dst]     = (bf16)(re * c - im * s);
    Qcat[dst + 1] = (bf16)(re * s + im * c);
}

// ---------------------------------------------------------------------------
// Causal flash attention (MLA absorbed form).
// Q per (b,h): Qcat[z] (2048 x 576). K per b: Kcat[b] (2048 x 576).
// V = Kcat[:, 0:512]. O -> ctx[z] (2048 x 512), already /l.
// Block: 256 thr (4 waves), KV tile = 32. Round-2 config (single KT buffer,
// Q from global/L2, depth-1 PV, ~128 VGPR, 42 KB LDS -> 2 blocks/CU resident).
//
// Causal load balance: grid.x = 16; each block processes TWO 64-row Q strips,
// qt = bx and qt = 31-bx, so every block does exactly (bx+1)+(32-bx) = 33
// KV tiles. 512 blocks = one full fill of the 2-blocks/CU residency -> no
// dispatch churn, no straggler tail.
// ---------------------------------------------------------------------------
#define ATTN_SCALE 0.07216878364870322f  // 1/sqrt(192)

__global__ __launch_bounds__(256, 2)
void flash_mla(const bf16* __restrict__ Qcat, const bf16* __restrict__ Kcat,
               bf16* __restrict__ ctx)
{
    __shared__ __attribute__((aligned(16))) bf16 KT[288 * 64];   // 36 KB
    __shared__ __attribute__((aligned(16))) bf16 P[4][16 * 40];  // per-wave P strip

    const int T = 2048;
    int z = blockIdx.y;          // b*16 + h
    int b = z >> 4;
    int bx = blockIdx.x;         // 0..15
    int tid = threadIdx.x;
    int w = tid >> 6, lane = tid & 63, l16 = lane & 15, quad = lane >> 4;

    const bf16* Qb = Qcat + (long long)z * T * 576;
    const bf16* Kb = Kcat + (long long)b * T * 576;
    bf16* Ob = ctx + (long long)z * T * 512;

    // staging source mapping (per lane): linear-dest order of the subtiled layout
    int srow = (lane >> 3) * 4 + ((lane >> 1) & 3);   // 0..31
    int scol = (lane & 1) * 8;                        // 0 or 8

    // QK^T B-fragment base (elements): col-tile (quad>>1), row-subtile l16>>2
    const bf16* kq0 = KT + ((quad >> 1) * 8 + (l16 >> 2)) * 64
                         + (l16 & 3) * 16 + (quad & 1) * 8;

    // PV tr-read base (bytes, low 32 bits of LDS address)
    unsigned trbase = (unsigned)(unsigned long long)(const void*)KT
                    + (unsigned)(quad * 256 + l16 * 8);

    for (int strip = 0; strip < 2; ++strip) {
        int qt = strip == 0 ? bx : 31 - bx;
        int qbase = qt * 64;
        const bf16* Qrow = Qb + (long long)(qbase + w * 16 + l16) * 576;

        f32x4 o[32] = {};
        float mrow[4], lrow[4];
#pragma unroll
        for (int r = 0; r < 4; ++r) { mrow[r] = -1e30f; lrow[r] = 0.f; }

        int ntiles = (qbase + 64) >> 5;
        for (int st = 0; st < ntiles; ++st) {
            int s0 = st << 5;

            __syncthreads();  // all readers of KT (QK + PV of prev iter) done
            {
                const bf16* gs = Kb + (long long)(s0 + srow) * 576 + scol;
#pragma unroll
                for (int it = 0; it < 9; ++it) {
                    int ci = it * 4 + w;                   // col-tile 0..35, wave-uniform
                    stage16(gs + ci * 16, KT + ci * 512);  // 1024 B per chunk
                }
            }
            __syncthreads();  // compiler drains vmcnt before barrier -> LDS ready

            // S strip: 16 rows x 32 cols (2 n-tiles), K = 576 = 18 steps
            f32x4 sa = {0.f, 0.f, 0.f, 0.f}, sb = {0.f, 0.f, 0.f, 0.f};
            __builtin_amdgcn_s_setprio(1);
#pragma unroll
            for (int kk = 0; kk < 18; ++kk) {
                bf16x8 a  = *(const bf16x8*)(Qrow + kk * 32 + quad * 8);
                bf16x8 b0 = *(const bf16x8*)(kq0 + kk * 1024);        // rows l16
                bf16x8 b1 = *(const bf16x8*)(kq0 + kk * 1024 + 256);  // rows 16+l16
                sa = MFMA16(a, b0, sa);
                sb = MFMA16(a, b1, sb);
            }
            __builtin_amdgcn_s_setprio(0);

            // online softmax (rows r = quad*4 + 0..3, cols s0 + {0,16} + l16)
            float alpha[4];
#pragma unroll
            for (int r = 0; r < 4; ++r) {
                int trow = qbase + w * 16 + quad * 4 + r;
                float v0 = sa[r] * ATTN_SCALE;
                float v1 = sb[r] * ATTN_SCALE;
                if (s0 + l16 > trow)      v0 = -1e30f;
                if (s0 + 16 + l16 > trow) v1 = -1e30f;
                float rm = fmaxf(v0, v1);
#pragma unroll
                for (int off = 1; off < 16; off <<= 1)
                    rm = fmaxf(rm, __shfl_xor(rm, off, 64));
                float mnew = fmaxf(mrow[r], rm);
                alpha[r] = __expf(mrow[r] - mnew);
                mrow[r] = mnew;
                float p0 = __expf(v0 - mnew);
                float p1 = __expf(v1 - mnew);
                float rs = p0 + p1;
#pragma unroll
                for (int off = 1; off < 16; off <<= 1)
                    rs += __shfl_xor(rs, off, 64);
                lrow[r] = lrow[r] * alpha[r] + rs;
                P[w][(quad * 4 + r) * 40 + l16]      = (bf16)p0;
                P[w][(quad * 4 + r) * 40 + 16 + l16] = (bf16)p1;
            }

            bf16x8 pa = *(const bf16x8*)(&P[w][l16 * 40 + quad * 8]);
            // drain P writes + pa before starting counted tr-read pipeline
            asm volatile("s_waitcnt lgkmcnt(0)" ::: "memory");
            __builtin_amdgcn_sched_barrier(0);

            // PV: software-pipelined (depth 1) hardware-transpose reads of V
            u16x4v L[2], H[2];
            tr_pair(trbase, L[0], H[0]);
            __builtin_amdgcn_s_setprio(1);
#pragma unroll
            for (int nt = 0; nt < 32; ++nt) {
                if (nt < 31) {
                    tr_pair(trbase + (unsigned)((nt + 1) * 1024), L[(nt + 1) & 1], H[(nt + 1) & 1]);
                    asm volatile("s_waitcnt lgkmcnt(2)" ::: "memory");
                } else {
                    asm volatile("s_waitcnt lgkmcnt(0)" ::: "memory");
                }
                __builtin_amdgcn_sched_barrier(0);
#pragma unroll
                for (int r = 0; r < 4; ++r) o[nt][r] *= alpha[r];
                o[nt] = MFMA16(pa, bv8(L[nt & 1], H[nt & 1]), o[nt]);
            }
            __builtin_amdgcn_s_setprio(0);
        }

        // epilogue: normalize and store ctx for this strip
#pragma unroll
        for (int nt = 0; nt < 32; ++nt)
#pragma unroll
            for (int r = 0; r < 4; ++r) {
                int trow = qbase + w * 16 + quad * 4 + r;
                Ob[(long long)trow * 512 + nt * 16 + l16] = (bf16)(o[nt][r] / lrow[r]);
            }
    }
}

// ---------------------------------------------------------------------------
extern "C" void kernel_launch(void* const* d_in, const int* in_sizes, int n_in,
                              void* d_out, int out_size, void* d_ws, size_t ws_size,
                              hipStream_t stream)
{
    const float* xf    = (const float*)d_in[0];
    const float* cosb  = (const float*)d_in[1];
    const float* sinb  = (const float*)d_in[2];
    const float* Wdqf  = (const float*)d_in[3];
    const float* Wuqf  = (const float*)d_in[4];
    const float* Wdkvf = (const float*)d_in[5];
    const float* Wukf  = (const float*)d_in[6];
    const float* Wuvf  = (const float*)d_in[7];
    const float* Wqrf  = (const float*)d_in[8];
    const float* Wkrf  = (const float*)d_in[9];
    const float* Wof   = (const float*)d_in[10];
    float* y = (float*)d_out;

    // workspace carve-up (bf16 intermediates + bf16 input copies, ~206 MB)
    char* ws = (char*)d_ws;
    bf16* c_q  = (bf16*)ws; ws += (size_t)4096 * 512 * 2;        // 4 MB
    bf16* Kcat = (bf16*)ws; ws += (size_t)4096 * 576 * 2;        // 4.7 MB
    bf16* krr  = (bf16*)ws; ws += (size_t)4096 * 64 * 2;         // 0.5 MB
    bf16* qrr  = (bf16*)ws; ws += (size_t)4096 * 1024 * 2;       // 8 MB
    bf16* vC2  = (bf16*)ws; ws += (size_t)2048 * 512 * 2;        // 2 MB
    bf16* keff = (bf16*)ws; ws += (size_t)16 * 512 * 512 * 2;    // 8 MB
    bf16* Qcat = (bf16*)ws; ws += (size_t)32 * 2048 * 576 * 2;   // 75.5 MB
    bf16* ctx  = (bf16*)ws; ws += (size_t)32 * 2048 * 512 * 2;   // 67 MB
    bf16* x    = (bf16*)ws; ws += (size_t)4096 * 2048 * 2;       // 16.8 MB
    bf16* Wdq  = (bf16*)ws; ws += (size_t)512 * 2048 * 2;        // 2 MB
    bf16* Wuq  = (bf16*)ws; ws += (size_t)2048 * 512 * 2;        // 2 MB
    bf16* Wdkv = (bf16*)ws; ws += (size_t)512 * 2048 * 2;        // 2 MB
    bf16* Wuk  = (bf16*)ws; ws += (size_t)2048 * 512 * 2;        // 2 MB
    bf16* Wuv  = (bf16*)ws; ws += (size_t)2048 * 512 * 2;        // 2 MB
    bf16* Wqr  = (bf16*)ws; ws += (size_t)1024 * 512 * 2;        // 1 MB
    bf16* Wkr  = (bf16*)ws; ws += (size_t)64 * 2048 * 2;         // 0.25 MB
    bf16* Wo   = (bf16*)ws; ws += (size_t)2048 * 2048 * 2;       // 8 MB

    dim3 blk(256);

    // 0. fp32 -> bf16 conversion of all matmul operands
    CvtArgs ca;
    ca.d[0] = {xf,    x,    (long long)4096 * 2048 / 4};
    ca.d[1] = {Wdqf,  Wdq,  (long long)512 * 2048 / 4};
    ca.d[2] = {Wuqf,  Wuq,  (long long)2048 * 512 / 4};
    ca.d[3] = {Wdkvf, Wdkv, (long long)512 * 2048 / 4};
    ca.d[4] = {Wukf,  Wuk,  (long long)2048 * 512 / 4};
    ca.d[5] = {Wuvf,  Wuv,  (long long)2048 * 512 / 4};
    ca.d[6] = {Wqrf,  Wqr,  (long long)1024 * 512 / 4};
    ca.d[7] = {Wkrf,  Wkr,  (long long)64 * 2048 / 4};
    ca.d[8] = {Wof,   Wo,   (long long)2048 * 2048 / 4};
    convert_many<<<dim3(512, 9), blk, 0, stream>>>(ca);

    // 1. c_q = x @ Wdq^T                       (4096 x 512, K=2048)
    gemm_nt<bf16><<<dim3(64, 8, 1), blk, 0, stream>>>(x, Wdq, c_q, 2048, 2048, 2048, 512,
                                                      0, 0, 0, 0, 0, 0, 1);
    // 2. c_kv -> Kcat[:, 0:512]                (4096 x 512, ldc=576)
    gemm_nt<bf16><<<dim3(64, 8, 1), blk, 0, stream>>>(x, Wdkv, Kcat, 2048, 2048, 2048, 576,
                                                      0, 0, 0, 0, 0, 0, 1);
    // 3. k_r_raw = x @ Wkr^T                   (4096 x 64)
    gemm_nt<bf16><<<dim3(64, 1, 1), blk, 0, stream>>>(x, Wkr, krr, 2048, 2048, 2048, 64,
                                                      0, 0, 0, 0, 0, 0, 1);
    // 4. q_r_raw = c_q @ Wqr^T                 (4096 x 1024, K=512)
    gemm_nt<bf16><<<dim3(64, 16, 1), blk, 0, stream>>>(c_q, Wqr, qrr, 512, 512, 512, 1024,
                                                       0, 0, 0, 0, 0, 0, 1);
    // 5. vC2 = Wo @ Wuv                        (2048 x 512, K=2048, NN)
    gemm_nn<<<dim3(32, 8, 1), blk, 0, stream>>>(Wo, Wuv, vC2, 2048, 2048, 512, 512,
                                                0, 0, 0, 0, 0, 0, 1);
    // 6. k_eff[h] = Wuq_r[h] @ Wuk_r[h]        (Z=16, 512 x 512, K=128, NN)
    gemm_nn<<<dim3(8, 8, 16), blk, 0, stream>>>(Wuq, Wuk, keff, 128, 2048, 512, 512,
                                                0, 128, 0, 65536, 0, 262144, 16);
    // 7. q_lat -> Qcat[:, 0:512]               (Z=32, 2048 x 512, K=512, NN)
    gemm_nn<<<dim3(32, 8, 32), blk, 0, stream>>>(c_q, keff, Qcat, 512, 512, 512, 576,
                                                 (long long)2048 * 512, 0,
                                                 0, 262144,
                                                 (long long)16 * 2048 * 576,
                                                 (long long)2048 * 576, 16);
    // 8. RoPE
    rope_k_kernel<<<dim3(512), blk, 0, stream>>>(krr, cosb, sinb, Kcat);
    rope_q_kernel<<<dim3(16384), blk, 0, stream>>>(qrr, cosb, sinb, Qcat);
    // 9. flash attention -> ctx  (strip-paired causal balance: 16 x 32 blocks)
    flash_mla<<<dim3(16, 32), blk, 0, stream>>>(Qcat, Kcat, ctx);
    // 10. y[b,t,h*128+d] = sum_k ctx[b,h,t,k] * vC2[h*128+d,k]   (Z=32, NT, fp32 out)
    gemm_nt<float><<<dim3(32, 2, 32), blk, 0, stream>>>(ctx, vC2, y, 512, 512, 512, 2048,
                                                        (long long)16 * 2048 * 512,
                                                        (long long)2048 * 512,
                                                        0, 65536,
                                                        (long long)2048 * 2048, 128, 16);
}

// Round 6
// 644.413 us; speedup vs baseline: 2.0504x; 1.0814x over previous
//
#include <hip/hip_runtime.h>

// MLA forward. Inputs/outputs fp32 (per reference); internal compute bf16 MFMA.
// B=2 T=2048 C=2048 NH=16 HS=128 NLQ=NLKV=512 DHR=64
//
// Fragment layouts (gfx950, verified per learn_hip m89/m120):
//   A[m][k]: m = lane&15, k = (lane>>4)*8 + j   (8 bf16 / lane)
//   B[k][n]: n = lane&15, k = (lane>>4)*8 + j
//   C/D[row][col]: col = lane&15, row = (lane>>4)*4 + reg

typedef __bf16 bf16;
typedef __bf16 bf16x8 __attribute__((ext_vector_type(8)));
typedef __bf16 bf16x4 __attribute__((ext_vector_type(4)));
typedef float f32x4 __attribute__((ext_vector_type(4)));
typedef unsigned short u16x4v __attribute__((ext_vector_type(4)));
typedef unsigned short u16x8v __attribute__((ext_vector_type(8)));

#define MFMA16(a, b, c) __builtin_amdgcn_mfma_f32_16x16x32_bf16((a), (b), (c), 0, 0, 0)

// async global->LDS 16B (linear dest: wave-uniform base + lane*16)
__device__ __forceinline__ void stage16(const bf16* g, bf16* lds)
{
    __builtin_amdgcn_global_load_lds(
        (const __attribute__((address_space(1))) unsigned int*)g,
        (__attribute__((address_space(3))) unsigned int*)lds,
        16, 0, 0);
}

// hardware transpose read: two ds_read_b64_tr_b16 covering one 8x16 bf16 subtile
// (two stacked 4x16 tiles, 128 B apart). Per 16-lane group, lane addr =
// window_base + l16*8 bytes; delivered elem j = window[j*16 + l16].
__device__ __forceinline__ void tr_pair(unsigned addr, u16x4v& lo, u16x4v& hi)
{
    asm volatile("ds_read_b64_tr_b16 %0, %2\n\t"
                 "ds_read_b64_tr_b16 %1, %2 offset:128"
                 : "=&v"(lo), "=&v"(hi)
                 : "v"(addr)
                 : "memory");
}

__device__ __forceinline__ bf16x8 bv8(u16x4v lo, u16x4v hi)
{
    u16x8v u = __builtin_shufflevector(lo, hi, 0, 1, 2, 3, 4, 5, 6, 7);
    return __builtin_bit_cast(bf16x8, u);
}

// ---------------------------------------------------------------------------
// fp32 -> bf16 batched conversion (9 tensors, descriptor struct by value)
// ---------------------------------------------------------------------------
struct CvtDesc { const float* src; bf16* dst; long long n4; };
struct CvtArgs { CvtDesc d[9]; };

__global__ void convert_many(CvtArgs a)
{
    CvtDesc d = a.d[blockIdx.y];
    long long i = (long long)blockIdx.x * blockDim.x + threadIdx.x;
    long long stride = (long long)gridDim.x * blockDim.x;
    for (; i < d.n4; i += stride) {
        f32x4 v = ((const f32x4*)d.src)[i];
        bf16x4 o;
        o[0] = (bf16)v[0]; o[1] = (bf16)v[1]; o[2] = (bf16)v[2]; o[3] = (bf16)v[3];
        ((bf16x4*)d.dst)[i] = o;
    }
}

// ---------------------------------------------------------------------------
// NT GEMM (64x64 tile): C[z][m][n] = sum_k A[m*lda+k] * B[n*ldb+k]
// Block: 256 thr = 4 waves; wave w owns rows w*16..w*16+15.
// ---------------------------------------------------------------------------
template <typename OutT>
__global__ __launch_bounds__(256, 4)
void gemm_nt(const bf16* __restrict__ A, const bf16* __restrict__ B,
             OutT* __restrict__ C, int K, int lda, int ldb, int ldc,
             long long sAb, long long sAh, long long sBb, long long sBh,
             long long sCb, long long sCh, int ZH)
{
    __shared__ __attribute__((aligned(16))) bf16 As[64 * 32];  // [m_local][k_local]
    __shared__ __attribute__((aligned(16))) bf16 Bs[64 * 32];  // [n_local][k_local]

    int z = blockIdx.z;
    int bb = z / ZH, hh = z % ZH;
    A += bb * sAb + hh * sAh;
    B += bb * sBb + hh * sBh;
    C += bb * sCb + hh * sCh;

    int tid = threadIdx.x;
    int w = tid >> 6, lane = tid & 63, l16 = lane & 15, quad = lane >> 4;
    int m0 = blockIdx.x * 64;
    int n0 = blockIdx.y * 64;

    int srow = w * 16 + (lane >> 2);
    int scol = (lane & 3) * 8;
    const bf16* gA = A + (long long)(m0 + srow) * lda + scol;
    const bf16* gB = B + (long long)(n0 + srow) * ldb + scol;
    bf16* lA = As + w * 512;   // wave-uniform dest base
    bf16* lB = Bs + w * 512;

    const bf16* fA = As + (w * 16 + l16) * 32 + quad * 8;
    f32x4 acc[4] = {};

    for (int k = 0; k < K; k += 32) {
        __syncthreads();
        stage16(gA + k, lA);
        stage16(gB + k, lB);
        __syncthreads();   // compiler drains vmcnt before barrier

        bf16x8 a = *(const bf16x8*)fA;
#pragma unroll
        for (int nt = 0; nt < 4; ++nt) {
            bf16x8 b = *(const bf16x8*)(Bs + (nt * 16 + l16) * 32 + quad * 8);
            acc[nt] = MFMA16(a, b, acc[nt]);
        }
    }
#pragma unroll
    for (int nt = 0; nt < 4; ++nt)
#pragma unroll
        for (int r = 0; r < 4; ++r) {
            int row = m0 + w * 16 + quad * 4 + r;
            int col = n0 + nt * 16 + l16;
            C[(long long)row * ldc + col] = (OutT)acc[nt][r];
        }
}

// ---------------------------------------------------------------------------
// NT GEMM (128x128 tile, m97 structure): 4 waves in 2x2, each 64x64 (4x4 frags).
// A,B K-tiles (128x32) staged linear via global_load_lds, 2 chunks/wave each.
// Needs grid >= ~512 blocks to profit (>=2 blocks/CU residency).
// ---------------------------------------------------------------------------
template <typename OutT>
__global__ __launch_bounds__(256, 2)
void gemm_nt128(const bf16* __restrict__ A, const bf16* __restrict__ B,
                OutT* __restrict__ C, int K, int lda, int ldb, int ldc,
                long long sAb, long long sAh, long long sBb, long long sBh,
                long long sCb, long long sCh, int ZH)
{
    __shared__ __attribute__((aligned(16))) bf16 As[128 * 32];  // [m][k] linear
    __shared__ __attribute__((aligned(16))) bf16 Bs[128 * 32];  // [n][k] linear

    int z = blockIdx.z;
    int bb = z / ZH, hh = z % ZH;
    A += bb * sAb + hh * sAh;
    B += bb * sBb + hh * sBh;
    C += bb * sCb + hh * sCh;

    int tid = threadIdx.x;
    int w = tid >> 6, lane = tid & 63, l16 = lane & 15, quad = lane >> 4;
    int wr = w >> 1, wc = w & 1;
    int m0 = blockIdx.x * 128;
    int n0 = blockIdx.y * 128;

    // staging: chunk c = j*4+w (8 x 1KB per matrix); lane covers
    // row c*16 + (lane>>2), cols (lane&3)*8..+7  -> dest = base + lane*16B
    int srow = lane >> 2;
    int scol = (lane & 3) * 8;
    const bf16* gA = A + (long long)(m0 + srow) * lda + scol;
    const bf16* gB = B + (long long)(n0 + srow) * ldb + scol;

    f32x4 acc[4][4] = {};

    for (int k = 0; k < K; k += 32) {
        __syncthreads();
#pragma unroll
        for (int j = 0; j < 2; ++j) {
            int c = j * 4 + w;
            stage16(gA + (long long)(c * 16) * lda + k, As + c * 512);
            stage16(gB + (long long)(c * 16) * ldb + k, Bs + c * 512);
        }
        __syncthreads();

        bf16x8 a[4], b[4];
#pragma unroll
        for (int t = 0; t < 4; ++t) {
            a[t] = *(const bf16x8*)(As + (wr * 64 + t * 16 + l16) * 32 + quad * 8);
            b[t] = *(const bf16x8*)(Bs + (wc * 64 + t * 16 + l16) * 32 + quad * 8);
        }
#pragma unroll
        for (int mt = 0; mt < 4; ++mt)
#pragma unroll
            for (int nt = 0; nt < 4; ++nt)
                acc[mt][nt] = MFMA16(a[mt], b[nt], acc[mt][nt]);
    }
#pragma unroll
    for (int mt = 0; mt < 4; ++mt)
#pragma unroll
        for (int nt = 0; nt < 4; ++nt)
#pragma unroll
            for (int r = 0; r < 4; ++r) {
                int row = m0 + wr * 64 + mt * 16 + quad * 4 + r;
                int col = n0 + wc * 64 + nt * 16 + l16;
                C[(long long)row * ldc + col] = (OutT)acc[mt][nt][r];
            }
}

// ---------------------------------------------------------------------------
// NN GEMM (64x64 tile): C[z][m][n] = sum_k A[m*lda+k] * B[k*ldb+n]
// B K-tile (32x64) staged via global_load_lds into 4x16-subtiled layout;
// B-fragments via ds_read_b64_tr_b16 pairs. A rows from global.
// ---------------------------------------------------------------------------
__global__ __launch_bounds__(256, 4)
void gemm_nn(const bf16* __restrict__ A, const bf16* __restrict__ B,
             bf16* __restrict__ C, int K, int lda, int ldb, int ldc,
             long long sAb, long long sAh, long long sBb, long long sBh,
             long long sCb, long long sCh, int ZH)
{
    __shared__ __attribute__((aligned(16))) bf16 BTs[2048];  // 4 KB subtiled

    int z = blockIdx.z;
    int bb = z / ZH, hh = z % ZH;
    A += bb * sAb + hh * sAh;
    B += bb * sBb + hh * sBh;
    C += bb * sCb + hh * sCh;

    int tid = threadIdx.x;
    int w = tid >> 6, lane = tid & 63, l16 = lane & 15, quad = lane >> 4;
    int m0 = blockIdx.x * 64;
    int n0 = blockIdx.y * 64;

    int srow = (lane >> 3) * 4 + ((lane >> 1) & 3);   // k row 0..31
    int scol = (lane & 1) * 8;                        // 0 or 8 within 16-col tile
    const bf16* gB = B + (long long)srow * ldb + n0 + w * 16 + scol;
    bf16* lB = BTs + w * 512;   // wave w stages col-tile w (1024 B)

    const bf16* Arow = A + (long long)(m0 + w * 16 + l16) * lda;
    unsigned trb = (unsigned)(unsigned long long)(const void*)BTs
                 + (unsigned)(quad * 256 + l16 * 8);

    f32x4 acc[4] = {};

    for (int k = 0; k < K; k += 32) {
        __syncthreads();
        stage16(gB + (long long)k * ldb, lB);
        __syncthreads();

        bf16x8 a = *(const bf16x8*)(Arow + k + quad * 8);
        u16x4v L0, H0, L1, H1, L2, H2, L3, H3;
        tr_pair(trb,        L0, H0);
        tr_pair(trb + 1024, L1, H1);
        tr_pair(trb + 2048, L2, H2);
        tr_pair(trb + 3072, L3, H3);
        asm volatile("s_waitcnt lgkmcnt(0)" ::: "memory");
        __builtin_amdgcn_sched_barrier(0);
        acc[0] = MFMA16(a, bv8(L0, H0), acc[0]);
        acc[1] = MFMA16(a, bv8(L1, H1), acc[1]);
        acc[2] = MFMA16(a, bv8(L2, H2), acc[2]);
        acc[3] = MFMA16(a, bv8(L3, H3), acc[3]);
    }
#pragma unroll
    for (int nt = 0; nt < 4; ++nt)
#pragma unroll
        for (int r = 0; r < 4; ++r) {
            int row = m0 + w * 16 + quad * 4 + r;
            int col = n0 + nt * 16 + l16;
            C[(long long)row * ldc + col] = (bf16)acc[nt][r];
        }
}

// ---------------------------------------------------------------------------
// NN GEMM (128x128 tile): A staged linear [128][32]; B (32x128) staged into
// 8 col-tile subtiled layout; B-fragments via tr_pair. 2x2 waves, 4x4 frags.
// ---------------------------------------------------------------------------
__global__ __launch_bounds__(256, 2)
void gemm_nn128(const bf16* __restrict__ A, const bf16* __restrict__ B,
                bf16* __restrict__ C, int K, int lda, int ldb, int ldc,
                long long sAb, long long sAh, long long sBb, long long sBh,
                long long sCb, long long sCh, int ZH)
{
    __shared__ __attribute__((aligned(16))) bf16 As[128 * 32];  // [m][k] linear
    __shared__ __attribute__((aligned(16))) bf16 BTs[4096];     // 8 col-tiles x 512

    int z = blockIdx.z;
    int bb = z / ZH, hh = z % ZH;
    A += bb * sAb + hh * sAh;
    B += bb * sBb + hh * sBh;
    C += bb * sCb + hh * sCh;

    int tid = threadIdx.x;
    int w = tid >> 6, lane = tid & 63, l16 = lane & 15, quad = lane >> 4;
    int wr = w >> 1, wc = w & 1;
    int m0 = blockIdx.x * 128;
    int n0 = blockIdx.y * 128;

    // A staging (linear): chunk c = j*4+w, row c*16+(lane>>2), col (lane&3)*8
    int sArow = lane >> 2;
    int sAcol = (lane & 3) * 8;
    const bf16* gA = A + (long long)(m0 + sArow) * lda + sAcol;

    // B staging (subtiled): chunk c = col-tile; lane: krow (lane>>3)*4+((lane>>1)&3),
    // col c*16 + (lane&1)*8
    int sBrow = (lane >> 3) * 4 + ((lane >> 1) & 3);
    int sBcol = (lane & 1) * 8;
    const bf16* gB = B + (long long)sBrow * ldb + n0 + sBcol;

    unsigned trb = (unsigned)(unsigned long long)(const void*)BTs
                 + (unsigned)(quad * 256 + l16 * 8);

    f32x4 acc[4][4] = {};

    for (int k = 0; k < K; k += 32) {
        __syncthreads();
#pragma unroll
        for (int j = 0; j < 2; ++j) {
            int c = j * 4 + w;
            stage16(gA + (long long)(c * 16) * lda + k, As + c * 512);
            stage16(gB + (long long)k * ldb + c * 16, BTs + c * 512);
        }
        __syncthreads();

        bf16x8 a[4];
#pragma unroll
        for (int mt = 0; mt < 4; ++mt)
            a[mt] = *(const bf16x8*)(As + (wr * 64 + mt * 16 + l16) * 32 + quad * 8);

        u16x4v L0, H0, L1, H1, L2, H2, L3, H3;
        unsigned tb = trb + (unsigned)(wc * 4096);   // wave's 4 col-tiles
        tr_pair(tb,        L0, H0);
        tr_pair(tb + 1024, L1, H1);
        tr_pair(tb + 2048, L2, H2);
        tr_pair(tb + 3072, L3, H3);
        asm volatile("s_waitcnt lgkmcnt(0)" ::: "memory");
        __builtin_amdgcn_sched_barrier(0);
        bf16x8 b[4] = { bv8(L0, H0), bv8(L1, H1), bv8(L2, H2), bv8(L3, H3) };
#pragma unroll
        for (int mt = 0; mt < 4; ++mt)
#pragma unroll
            for (int nt = 0; nt < 4; ++nt)
                acc[mt][nt] = MFMA16(a[mt], b[nt], acc[mt][nt]);
    }
#pragma unroll
    for (int mt = 0; mt < 4; ++mt)
#pragma unroll
        for (int nt = 0; nt < 4; ++nt)
#pragma unroll
            for (int r = 0; r < 4; ++r) {
                int row = m0 + wr * 64 + mt * 16 + quad * 4 + r;
                int col = n0 + wc * 64 + nt * 16 + l16;
                C[(long long)row * ldc + col] = (bf16)acc[mt][nt][r];
            }
}

// ---------------------------------------------------------------------------
// RoPE kernels: write rotated halves into cols 512..575 of Kcat / Qcat.
// ---------------------------------------------------------------------------
__global__ void rope_k_kernel(const bf16* __restrict__ krr, const float* __restrict__ cosb,
                              const float* __restrict__ sinb, bf16* __restrict__ Kcat)
{
    int i = blockIdx.x * 256 + threadIdx.x;  // B*T*32 = 131072
    int pr = i & 31;
    int row = i >> 5;            // b*2048 + t
    int t = row & 2047;
    float re = (float)krr[row * 64 + 2 * pr];
    float im = (float)krr[row * 64 + 2 * pr + 1];
    float c = cosb[t * 32 + pr];
    float s = sinb[t * 32 + pr];
    long long base = (long long)row * 576 + 512 + 2 * pr;
    Kcat[base]     = (bf16)(re * c - im * s);
    Kcat[base + 1] = (bf16)(re * s + im * c);
}

__global__ void rope_q_kernel(const bf16* __restrict__ qrr, const float* __restrict__ cosb,
                              const float* __restrict__ sinb, bf16* __restrict__ Qcat)
{
    int i = blockIdx.x * 256 + threadIdx.x;  // B*T*NH*32 = 4194304
    int pr = i & 31;
    int h = (i >> 5) & 15;
    int t = (i >> 9) & 2047;
    int b = i >> 20;
    long long src = ((long long)(b * 2048 + t)) * 1024 + h * 64 + 2 * pr;
    float re = (float)qrr[src];
    float im = (float)qrr[src + 1];
    float c = cosb[t * 32 + pr];
    float s = sinb[t * 32 + pr];
    long long dst = ((long long)((b * 16 + h) * 2048 + t)) * 576 + 512 + 2 * pr;
    Qcat[dst]     = (bf16)(re * c - im * s);
    Qcat[dst + 1] = (bf16)(re * s + im * c);
}

// ---------------------------------------------------------------------------
// Causal flash attention (MLA absorbed form). Round-5 config (best: 343 us).
// Strip-paired causal balance: each block does qt=bx and qt=31-bx (66 tiles).
// ---------------------------------------------------------------------------
#define ATTN_SCALE 0.07216878364870322f  // 1/sqrt(192)

__global__ __launch_bounds__(256, 2)
void flash_mla(const bf16* __restrict__ Qcat, const bf16* __restrict__ Kcat,
               bf16* __restrict__ ctx)
{
    __shared__ __attribute__((aligned(16))) bf16 KT[288 * 64];   // 36 KB
    __shared__ __attribute__((aligned(16))) bf16 P[4][16 * 40];  // per-wave P strip

    const int T = 2048;
    int z = blockIdx.y;          // b*16 + h
    int b = z >> 4;
    int bx = blockIdx.x;         // 0..15
    int tid = threadIdx.x;
    int w = tid >> 6, lane = tid & 63, l16 = lane & 15, quad = lane >> 4;

    const bf16* Qb = Qcat + (long long)z * T * 576;
    const bf16* Kb = Kcat + (long long)b * T * 576;
    bf16* Ob = ctx + (long long)z * T * 512;

    // staging source mapping (per lane): linear-dest order of the subtiled layout
    int srow = (lane >> 3) * 4 + ((lane >> 1) & 3);   // 0..31
    int scol = (lane & 1) * 8;                        // 0 or 8

    // QK^T B-fragment base (elements): col-tile (quad>>1), row-subtile l16>>2
    const bf16* kq0 = KT + ((quad >> 1) * 8 + (l16 >> 2)) * 64
                         + (l16 & 3) * 16 + (quad & 1) * 8;

    // PV tr-read base (bytes, low 32 bits of LDS address)
    unsigned trbase = (unsigned)(unsigned long long)(const void*)KT
                    + (unsigned)(quad * 256 + l16 * 8);

    for (int strip = 0; strip < 2; ++strip) {
        int qt = strip == 0 ? bx : 31 - bx;
        int qbase = qt * 64;
        const bf16* Qrow = Qb + (long long)(qbase + w * 16 + l16) * 576;

        f32x4 o[32] = {};
        float mrow[4], lrow[4];
#pragma unroll
        for (int r = 0; r < 4; ++r) { mrow[r] = -1e30f; lrow[r] = 0.f; }

        int ntiles = (qbase + 64) >> 5;
        for (int st = 0; st < ntiles; ++st) {
            int s0 = st << 5;

            __syncthreads();  // all readers of KT (QK + PV of prev iter) done
            {
                const bf16* gs = Kb + (long long)(s0 + srow) * 576 + scol;
#pragma unroll
                for (int it = 0; it < 9; ++it) {
                    int ci = it * 4 + w;                   // col-tile 0..35, wave-uniform
                    stage16(gs + ci * 16, KT + ci * 512);  // 1024 B per chunk
                }
            }
            __syncthreads();  // compiler drains vmcnt before barrier -> LDS ready

            // S strip: 16 rows x 32 cols (2 n-tiles), K = 576 = 18 steps
            f32x4 sa = {0.f, 0.f, 0.f, 0.f}, sb = {0.f, 0.f, 0.f, 0.f};
            __builtin_amdgcn_s_setprio(1);
#pragma unroll
            for (int kk = 0; kk < 18; ++kk) {
                bf16x8 a  = *(const bf16x8*)(Qrow + kk * 32 + quad * 8);
                bf16x8 b0 = *(const bf16x8*)(kq0 + kk * 1024);        // rows l16
                bf16x8 b1 = *(const bf16x8*)(kq0 + kk * 1024 + 256);  // rows 16+l16
                sa = MFMA16(a, b0, sa);
                sb = MFMA16(a, b1, sb);
            }
            __builtin_amdgcn_s_setprio(0);

            // online softmax (rows r = quad*4 + 0..3, cols s0 + {0,16} + l16)
            float alpha[4];
#pragma unroll
            for (int r = 0; r < 4; ++r) {
                int trow = qbase + w * 16 + quad * 4 + r;
                float v0 = sa[r] * ATTN_SCALE;
                float v1 = sb[r] * ATTN_SCALE;
                if (s0 + l16 > trow)      v0 = -1e30f;
                if (s0 + 16 + l16 > trow) v1 = -1e30f;
                float rm = fmaxf(v0, v1);
#pragma unroll
                for (int off = 1; off < 16; off <<= 1)
                    rm = fmaxf(rm, __shfl_xor(rm, off, 64));
                float mnew = fmaxf(mrow[r], rm);
                alpha[r] = __expf(mrow[r] - mnew);
                mrow[r] = mnew;
                float p0 = __expf(v0 - mnew);
                float p1 = __expf(v1 - mnew);
                float rs = p0 + p1;
#pragma unroll
                for (int off = 1; off < 16; off <<= 1)
                    rs += __shfl_xor(rs, off, 64);
                lrow[r] = lrow[r] * alpha[r] + rs;
                P[w][(quad * 4 + r) * 40 + l16]      = (bf16)p0;
                P[w][(quad * 4 + r) * 40 + 16 + l16] = (bf16)p1;
            }

            bf16x8 pa = *(const bf16x8*)(&P[w][l16 * 40 + quad * 8]);
            // drain P writes + pa before starting counted tr-read pipeline
            asm volatile("s_waitcnt lgkmcnt(0)" ::: "memory");
            __builtin_amdgcn_sched_barrier(0);

            // PV: software-pipelined (depth 1) hardware-transpose reads of V
            u16x4v L[2], H[2];
            tr_pair(trbase, L[0], H[0]);
            __builtin_amdgcn_s_setprio(1);
#pragma unroll
            for (int nt = 0; nt < 32; ++nt) {
                if (nt < 31) {
                    tr_pair(trbase + (unsigned)((nt + 1) * 1024), L[(nt + 1) & 1], H[(nt + 1) & 1]);
                    asm volatile("s_waitcnt lgkmcnt(2)" ::: "memory");
                } else {
                    asm volatile("s_waitcnt lgkmcnt(0)" ::: "memory");
                }
                __builtin_amdgcn_sched_barrier(0);
#pragma unroll
                for (int r = 0; r < 4; ++r) o[nt][r] *= alpha[r];
                o[nt] = MFMA16(pa, bv8(L[nt & 1], H[nt & 1]), o[nt]);
            }
            __builtin_amdgcn_s_setprio(0);
        }

        // epilogue: normalize and store ctx for this strip
#pragma unroll
        for (int nt = 0; nt < 32; ++nt)
#pragma unroll
            for (int r = 0; r < 4; ++r) {
                int trow = qbase + w * 16 + quad * 4 + r;
                Ob[(long long)trow * 512 + nt * 16 + l16] = (bf16)(o[nt][r] / lrow[r]);
            }
    }
}

// ---------------------------------------------------------------------------
extern "C" void kernel_launch(void* const* d_in, const int* in_sizes, int n_in,
                              void* d_out, int out_size, void* d_ws, size_t ws_size,
                              hipStream_t stream)
{
    const float* xf    = (const float*)d_in[0];
    const float* cosb  = (const float*)d_in[1];
    const float* sinb  = (const float*)d_in[2];
    const float* Wdqf  = (const float*)d_in[3];
    const float* Wuqf  = (const float*)d_in[4];
    const float* Wdkvf = (const float*)d_in[5];
    const float* Wukf  = (const float*)d_in[6];
    const float* Wuvf  = (const float*)d_in[7];
    const float* Wqrf  = (const float*)d_in[8];
    const float* Wkrf  = (const float*)d_in[9];
    const float* Wof   = (const float*)d_in[10];
    float* y = (float*)d_out;

    // workspace carve-up (bf16 intermediates + bf16 input copies, ~206 MB)
    char* ws = (char*)d_ws;
    bf16* c_q  = (bf16*)ws; ws += (size_t)4096 * 512 * 2;        // 4 MB
    bf16* Kcat = (bf16*)ws; ws += (size_t)4096 * 576 * 2;        // 4.7 MB
    bf16* krr  = (bf16*)ws; ws += (size_t)4096 * 64 * 2;         // 0.5 MB
    bf16* qrr  = (bf16*)ws; ws += (size_t)4096 * 1024 * 2;       // 8 MB
    bf16* vC2  = (bf16*)ws; ws += (size_t)2048 * 512 * 2;        // 2 MB
    bf16* keff = (bf16*)ws; ws += (size_t)16 * 512 * 512 * 2;    // 8 MB
    bf16* Qcat = (bf16*)ws; ws += (size_t)32 * 2048 * 576 * 2;   // 75.5 MB
    bf16* ctx  = (bf16*)ws; ws += (size_t)32 * 2048 * 512 * 2;   // 67 MB
    bf16* x    = (bf16*)ws; ws += (size_t)4096 * 2048 * 2;       // 16.8 MB
    bf16* Wdq  = (bf16*)ws; ws += (size_t)512 * 2048 * 2;        // 2 MB
    bf16* Wuq  = (bf16*)ws; ws += (size_t)2048 * 512 * 2;        // 2 MB
    bf16* Wdkv = (bf16*)ws; ws += (size_t)512 * 2048 * 2;        // 2 MB
    bf16* Wuk  = (bf16*)ws; ws += (size_t)2048 * 512 * 2;        // 2 MB
    bf16* Wuv  = (bf16*)ws; ws += (size_t)2048 * 512 * 2;        // 2 MB
    bf16* Wqr  = (bf16*)ws; ws += (size_t)1024 * 512 * 2;        // 1 MB
    bf16* Wkr  = (bf16*)ws; ws += (size_t)64 * 2048 * 2;         // 0.25 MB
    bf16* Wo   = (bf16*)ws; ws += (size_t)2048 * 2048 * 2;       // 8 MB

    dim3 blk(256);

    // 0. fp32 -> bf16 conversion of all matmul operands
    CvtArgs ca;
    ca.d[0] = {xf,    x,    (long long)4096 * 2048 / 4};
    ca.d[1] = {Wdqf,  Wdq,  (long long)512 * 2048 / 4};
    ca.d[2] = {Wuqf,  Wuq,  (long long)2048 * 512 / 4};
    ca.d[3] = {Wdkvf, Wdkv, (long long)512 * 2048 / 4};
    ca.d[4] = {Wukf,  Wuk,  (long long)2048 * 512 / 4};
    ca.d[5] = {Wuvf,  Wuv,  (long long)2048 * 512 / 4};
    ca.d[6] = {Wqrf,  Wqr,  (long long)1024 * 512 / 4};
    ca.d[7] = {Wkrf,  Wkr,  (long long)64 * 2048 / 4};
    ca.d[8] = {Wof,   Wo,   (long long)2048 * 2048 / 4};
    convert_many<<<dim3(512, 9), blk, 0, stream>>>(ca);

    // 1. c_q = x @ Wdq^T                       (4096 x 512, K=2048)
    gemm_nt<bf16><<<dim3(64, 8, 1), blk, 0, stream>>>(x, Wdq, c_q, 2048, 2048, 2048, 512,
                                                      0, 0, 0, 0, 0, 0, 1);
    // 2. c_kv -> Kcat[:, 0:512]                (4096 x 512, ldc=576)
    gemm_nt<bf16><<<dim3(64, 8, 1), blk, 0, stream>>>(x, Wdkv, Kcat, 2048, 2048, 2048, 576,
                                                      0, 0, 0, 0, 0, 0, 1);
    // 3. k_r_raw = x @ Wkr^T                   (4096 x 64)
    gemm_nt<bf16><<<dim3(64, 1, 1), blk, 0, stream>>>(x, Wkr, krr, 2048, 2048, 2048, 64,
                                                      0, 0, 0, 0, 0, 0, 1);
    // 4. q_r_raw = c_q @ Wqr^T                 (4096 x 1024, K=512)
    gemm_nt<bf16><<<dim3(64, 16, 1), blk, 0, stream>>>(c_q, Wqr, qrr, 512, 512, 512, 1024,
                                                       0, 0, 0, 0, 0, 0, 1);
    // 5. vC2 = Wo @ Wuv                        (2048 x 512, K=2048, NN)
    gemm_nn<<<dim3(32, 8, 1), blk, 0, stream>>>(Wo, Wuv, vC2, 2048, 2048, 512, 512,
                                                0, 0, 0, 0, 0, 0, 1);
    // 6. k_eff[h] = Wuq_r[h] @ Wuk_r[h]        (Z=16, 512 x 512, K=128, NN)
    gemm_nn<<<dim3(8, 8, 16), blk, 0, stream>>>(Wuq, Wuk, keff, 128, 2048, 512, 512,
                                                0, 128, 0, 65536, 0, 262144, 16);
    // 7. q_lat -> Qcat[:, 0:512]               (Z=32, 2048 x 512, K=512, NN 128^2)
    gemm_nn128<<<dim3(16, 4, 32), blk, 0, stream>>>(c_q, keff, Qcat, 512, 512, 512, 576,
                                                    (long long)2048 * 512, 0,
                                                    0, 262144,
                                                    (long long)16 * 2048 * 576,
                                                    (long long)2048 * 576, 16);
    // 8. RoPE
    rope_k_kernel<<<dim3(512), blk, 0, stream>>>(krr, cosb, sinb, Kcat);
    rope_q_kernel<<<dim3(16384), blk, 0, stream>>>(qrr, cosb, sinb, Qcat);
    // 9. flash attention -> ctx  (strip-paired causal balance: 16 x 32 blocks)
    flash_mla<<<dim3(16, 32), blk, 0, stream>>>(Qcat, Kcat, ctx);
    // 10. y = ctx @ vC2^T per head             (Z=32, 2048 x 128, K=512, NT 128^2)
    gemm_nt128<float><<<dim3(16, 1, 32), blk, 0, stream>>>(ctx, vC2, y, 512, 512, 512, 2048,
                                                           (long long)16 * 2048 * 512,
                                                           (long long)2048 * 512,
                                                           0, 65536,
                                                           (long long)2048 * 2048, 128, 16);
}